// Round 9
// baseline (97.089 us; speedup 1.0000x reference)
//
#include <hip/hip_runtime.h>
#include <math.h>

#define NB 256
#define NIMG 1561
#define RIRLEN 8000
#define PADI 40
#define NTHREADS 1024
#define NWAVES (NTHREADS / 64)
#define NBKT 505          // bucket = (base+80)>>4, base in [-40,7999] -> 2..504
#define NSTARTP 512       // s_start padded to 512 (entries >=505 = total)
#define NTILE 63          // 128-sample tiles; tile q covers samples [128q,128q+128)

// ---------------------------------------------------------------------------
// Compile-time image-lattice table: all g in [-10,10]^3 with |g|_1 <= 10,
// meshgrid(ij) lexicographic order. Packed:
//   bits 0-4: x+10, 5-9: y+10, 10-14: z+10, 15-19: |g|_1
// ---------------------------------------------------------------------------
struct ImgTab { unsigned int v[NIMG]; };

constexpr ImgTab build_tab() {
    ImgTab t{};
    int n = 0;
    for (int x = -10; x <= 10; ++x)
        for (int y = -10; y <= 10; ++y)
            for (int z = -10; z <= 10; ++z) {
                int ax = x < 0 ? -x : x;
                int ay = y < 0 ? -y : y;
                int az = z < 0 ? -z : z;
                int l1 = ax + ay + az;
                if (l1 <= 10) {
                    t.v[n++] = (unsigned)(x + 10) | ((unsigned)(y + 10) << 5) |
                               ((unsigned)(z + 10) << 10) | ((unsigned)l1 << 15);
                }
            }
    return t;
}

constexpr int tab_count() {
    int n = 0;
    for (int x = -10; x <= 10; ++x)
        for (int y = -10; y <= 10; ++y)
            for (int z = -10; z <= 10; ++z) {
                int ax = x < 0 ? -x : x;
                int ay = y < 0 ? -y : y;
                int az = z < 0 ? -z : z;
                if (ax + ay + az <= 10) ++n;
            }
    return n;
}
static_assert(tab_count() == NIMG, "image count mismatch");

__constant__ ImgTab c_tab = build_tab();

// Record per image (bucket-sorted): (A, B, C, d)
//   A = 0.5*S, B = 0.5*S*cos(pi*d/40), C = 0.5*S*sin(pi*d/40)
//   S = (-1)^dlc * amp * sin(pi*frac)/pi,  d = delay (exact, NON-integer)
// Tap at sample n: (-1)^n * (A + B*cos(pi*n/40) + C*sin(pi*n/40)) / (n-d),
// masked to |n-d| < 40.  frac==0 records are emitted as exact spikes instead.
//
// Phase 2: tile q = 128 samples; lane l owns n0=128q+l and n1=n0+64.
// Records for buckets [8q, 8q+13) are loaded 64-at-a-time with ONE stride-1
// ds_read_b128 (lane l holds record k+l), then iterated via v_readlane
// broadcasts -> zero DS traffic in the inner loop. Over-reads past the
// window are harmless: the |x|<40 mask provably kills any record whose
// bucket lies outside [8q, 8q+13).
__global__ __launch_bounds__(NTHREADS) void
rir_kernel(const float* __restrict__ in, float* __restrict__ out) {
    __shared__ float4 s_rec[NIMG + 1];   // +1 dummy (far-away) record
    __shared__ float  s_trpow[11];
    __shared__ int    s_hist[NSTARTP];
    __shared__ int    s_start[NSTARTP];
    __shared__ int    s_cursor[NBKT];
    __shared__ int    s_qnext;
    __shared__ int    s_nspike;
    __shared__ int    s_spike_idx[64];
    __shared__ float  s_spike_amp[64];

    const int b   = blockIdx.x;
    const int tid = threadIdx.x;
    const float* p = in + b * 10;

    if (tid < NSTARTP) s_hist[tid] = 0;
    if (tid == 0) {
        float tr = sqrtf(1.0f - p[9]);
        float pw = 1.0f;
        for (int k = 0; k <= 10; ++k) { s_trpow[k] = pw; pw *= tr; }
        s_nspike = 0;
        s_qnext  = NWAVES;
        s_rec[NIMG] = make_float4(0.0f, 0.0f, 0.0f, -1.0e6f);  // dummy
    }
    __syncthreads();

    const float rx = p[0], ry = p[1], rz = p[2];
    const float mx = p[3] * rx, my = p[4] * ry, mz = p[5] * rz;
    const float sx = p[6] * rx, sy = p[7] * ry, sz = p[8] * rz;
    const float K = 16000.0f / 343.0f;
    const float INV_PI = 0.31830988618379067154f;

    // ---- phase 1: per-image parameters + bucket histogram ----
    float4 rec[2];
    int ibkt[2]  = {0, 0};
    bool ivalid[2] = {false, false};

    for (int u = 0; u < 2; ++u) {
        int i = tid + u * NTHREADS;
        if (i < NIMG) {
            unsigned v = c_tab.v[i];
            int gx = (int)(v & 31u) - 10;
            int gy = (int)((v >> 5) & 31u) - 10;
            int gz = (int)((v >> 10) & 31u) - 10;
            int l1 = (int)(v >> 15);

            float ix = (gx & 1) ? rx * (float)(gx + 1) - sx : rx * (float)gx + sx;
            float iy = (gy & 1) ? ry * (float)(gy + 1) - sy : ry * (float)gy + sy;
            float iz = (gz & 1) ? rz * (float)(gz + 1) - sz : rz * (float)gz + sz;

            float dx = ix - mx, dy = iy - my, dz = iz - mz;
            float dist = sqrtf(dx * dx + dy * dy + dz * dz);

            float amp  = s_trpow[l1] * __builtin_amdgcn_rcpf(dist);
            float d    = dist * K;
            float dlc  = ceilf(d);
            float frac = dlc - d;                 // exact (Sterbenz)
            int   idlc = (int)dlc;
            int   base = idlc - PADI;

            if (base < RIRLEN) {
                if (frac == 0.0f) {
                    // integer-grid delay: exact single spike of amp at idlc
                    if (idlc < RIRLEN) {
                        int sp = atomicAdd(&s_nspike, 1);
                        if (sp < 64) { s_spike_idx[sp] = idlc; s_spike_amp[sp] = amp; }
                    }
                } else {
                    float spf = (frac < 1.0e-3f) ? frac : (sinpif(frac) * INV_PI);
                    float S   = amp * spf;
                    if (idlc & 1) S = -S;         // (-1)^dlc
                    float hS  = 0.5f * S;
                    float cd  = cospif(d * 0.025f);
                    float sd  = sinpif(d * 0.025f);
                    rec[u] = make_float4(hS, hS * cd, hS * sd, d);
                    ibkt[u]   = (base + 80) >> 4;
                    ivalid[u] = true;
                    atomicAdd(&s_hist[ibkt[u]], 1);
                }
            }
        }
    }
    __syncthreads();

    // ---- single-wave exclusive scan of the 505-bucket histogram ----
    // lane l owns buckets [8l, 8l+8); local prefix + shfl_up wave scan.
    if (tid < 64) {
        int base_i = tid * 8;
        int v[8], pre[8];
        int run = 0;
#pragma unroll
        for (int j = 0; j < 8; ++j) {
            v[j] = s_hist[base_i + j];            // padded entries are 0
            pre[j] = run;
            run += v[j];
        }
        int t = run;
#pragma unroll
        for (int d2 = 1; d2 < 64; d2 <<= 1) {
            int y = __shfl_up(t, d2);
            if (tid >= d2) t += y;
        }
        int excl = t - run;
#pragma unroll
        for (int j = 0; j < 8; ++j) {
            int idx = base_i + j;
            int sv  = excl + pre[j];              // exclusive prefix at idx
            s_start[idx] = sv;
            if (idx < NBKT) s_cursor[idx] = sv;
        }
    }
    __syncthreads();

    // ---- scatter records into bucket-sorted order ----
    for (int u = 0; u < 2; ++u) {
        if (ivalid[u]) {
            int pos = atomicAdd(&s_cursor[ibkt[u]], 1);
            s_rec[pos] = rec[u];
        }
    }
    __syncthreads();

    // ---- phase 2: gather, readlane-broadcast records ----
    const int wave = tid >> 6;
    const int lane = tid & 63;
    const float sgn = (lane & 1) ? -1.0f : 1.0f;  // (-1)^n for both samples
    const float c64 =  0.30901699437494742410f;   // cos(1.6*pi)
    const float s64 = -0.95105651629515357212f;   // sin(1.6*pi)
    float* __restrict__ ob = out + (size_t)b * RIRLEN;

    int q = wave;
    while (q < NTILE) {
        const int n0 = (q << 7) + lane;           // tile sample, lane-owned
        const int n1 = n0 + 64;
        const float fn0 = (float)n0;
        const float cn0 = cospif(fn0 * 0.025f), sn0 = sinpif(fn0 * 0.025f);
        const float cnn1 = cn0 * c64 - sn0 * s64; // cos(pi*n1/40)
        const float snn1 = sn0 * c64 + cn0 * s64; // sin(pi*n1/40)

        const int lo = s_start[8 * q];
        const int hi = s_start[8 * q + 13];       // max index 509 < 512

        float acc0 = 0.0f, acc1 = 0.0f;
        for (int k = lo; k < hi; k += 64) {
            // one stride-1 ds_read_b128 loads up to 64 records; lane l
            // holds record k+l. Only j < jmax are consumed via readlane.
            int idx = k + lane;
            idx = (idx <= NIMG) ? idx : NIMG;
            float4 rr = s_rec[idx];
            const int jmax = ((hi - k) < 64) ? (hi - k) : 64;
#pragma clang loop unroll_count(4)
            for (int j = 0; j < jmax; ++j) {
                float A = __int_as_float(__builtin_amdgcn_readlane(__float_as_int(rr.x), j));
                float B = __int_as_float(__builtin_amdgcn_readlane(__float_as_int(rr.y), j));
                float C = __int_as_float(__builtin_amdgcn_readlane(__float_as_int(rr.z), j));
                float D = __int_as_float(__builtin_amdgcn_readlane(__float_as_int(rr.w), j));
                float y0 = D - fn0;               // = -x0, never 0
                float y1 = y0 - 64.0f;            // = -x1
                float pr = __builtin_amdgcn_rcpf(y0 * y1);  // 1/(x0*x1)
                float t0 = fmaf(B, cn0,  A); t0 = fmaf(C, sn0,  t0);
                float t1 = fmaf(B, cnn1, A); t1 = fmaf(C, snn1, t1);
                t0 = (fabsf(y0) < 40.0f) ? t0 : 0.0f;   // hann support mask
                t1 = (fabsf(y1) < 40.0f) ? t1 : 0.0f;
                // tap0 = t0/x0 = -t0*y1*pr ; tap1 = t1/x1 = -t1*y0*pr
                acc0 = fmaf(-(t0 * y1), pr, acc0);
                acc1 = fmaf(-(t1 * y0), pr, acc1);
            }
        }
        if (n0 < RIRLEN) ob[n0] = acc0 * sgn;
        if (n1 < RIRLEN) ob[n1] = acc1 * sgn;

        // steal next tile
        int nq;
        if (lane == 0) nq = atomicAdd(&s_qnext, 1);
        q = __shfl(nq, 0);
    }

    // ---- spikes (frac==0, rare): add after stores ----
    __syncthreads();
    int nsp = s_nspike; nsp = (nsp < 64) ? nsp : 64;
    if (tid < nsp) atomicAdd(&ob[s_spike_idx[tid]], s_spike_amp[tid]);

    // time-of-arrival
    if (tid == 0) {
        float dx = mx - sx, dy = my - sy, dz = mz - sz;
        out[(size_t)NB * RIRLEN + b] = 40.0f + sqrtf(dx * dx + dy * dy + dz * dz) * K;
    }
}

extern "C" void kernel_launch(void* const* d_in, const int* in_sizes, int n_in,
                              void* d_out, int out_size, void* d_ws, size_t ws_size,
                              hipStream_t stream) {
    const float* in = (const float*)d_in[0];
    float* out = (float*)d_out;
    rir_kernel<<<dim3(NB), dim3(NTHREADS), 0, stream>>>(in, out);
}

// Round 10
// 95.801 us; speedup vs baseline: 1.0134x; 1.0134x over previous
//
#include <hip/hip_runtime.h>
#include <math.h>

#define NB 256
#define NIMG 1561
#define RIRLEN 8000
#define PADI 40
#define NTHREADS 1024
#define NWAVES (NTHREADS / 64)
#define NBKT 505          // bucket = (base+80)>>4, base in [-40,7999] -> 2..504
#define NSTARTP 512       // s_start padded to 512 (entries >=505 = total)
#define NTILE 63          // 128-sample tiles; tile t covers [128t, 128t+128)
#define NPAIRS 32         // pair q = tiles (2q, 2q+1); tile 63 is empty

// ---------------------------------------------------------------------------
// Compile-time image-lattice table: all g in [-10,10]^3 with |g|_1 <= 10,
// meshgrid(ij) lexicographic order. Packed:
//   bits 0-4: x+10, 5-9: y+10, 10-14: z+10, 15-19: |g|_1
// ---------------------------------------------------------------------------
struct ImgTab { unsigned int v[NIMG]; };

constexpr ImgTab build_tab() {
    ImgTab t{};
    int n = 0;
    for (int x = -10; x <= 10; ++x)
        for (int y = -10; y <= 10; ++y)
            for (int z = -10; z <= 10; ++z) {
                int ax = x < 0 ? -x : x;
                int ay = y < 0 ? -y : y;
                int az = z < 0 ? -z : z;
                int l1 = ax + ay + az;
                if (l1 <= 10) {
                    t.v[n++] = (unsigned)(x + 10) | ((unsigned)(y + 10) << 5) |
                               ((unsigned)(z + 10) << 10) | ((unsigned)l1 << 15);
                }
            }
    return t;
}

constexpr int tab_count() {
    int n = 0;
    for (int x = -10; x <= 10; ++x)
        for (int y = -10; y <= 10; ++y)
            for (int z = -10; z <= 10; ++z) {
                int ax = x < 0 ? -x : x;
                int ay = y < 0 ? -y : y;
                int az = z < 0 ? -z : z;
                if (ax + ay + az <= 10) ++n;
            }
    return n;
}
static_assert(tab_count() == NIMG, "image count mismatch");

__constant__ ImgTab c_tab = build_tab();

// Record per image (bucket-sorted): (A, B, C, d)
//   A = 0.5*S, B = 0.5*S*cos(pi*d/40), C = 0.5*S*sin(pi*d/40)
//   S = (-1)^dlc * amp * sin(pi*frac)/pi,  d = delay (exact, NON-integer)
// Tap at sample n: (-1)^n * (A + B*cos(pi*n/40) + C*sin(pi*n/40)) / (n-d),
// masked to |n-d| < 40.  frac==0 records are emitted as exact spikes instead.
//
// Phase 2: wave pair q: lanes 0-31 serve tile 2q, lanes 32-63 tile 2q+1.
// Each lane owns 4 samples (l5, +32, +64, +96) of its 128-sample tile.
// One ds_read_b128 per iter carries TWO distinct addresses (2-way: free).
__global__ __launch_bounds__(NTHREADS) void
rir_kernel(const float* __restrict__ in, float* __restrict__ out) {
    __shared__ float4 s_rec[NIMG + 1];   // +1 dummy (far-away) record
    __shared__ float  s_trpow[11];
    __shared__ int    s_hist[NSTARTP];
    __shared__ int    s_start[NSTARTP];
    __shared__ int    s_cursor[NBKT];
    __shared__ int    s_qnext;
    __shared__ int    s_nspike;
    __shared__ int    s_spike_idx[64];
    __shared__ float  s_spike_amp[64];

    const int b   = blockIdx.x;
    const int tid = threadIdx.x;
    const float* p = in + b * 10;

    if (tid < NSTARTP) s_hist[tid] = 0;
    if (tid == 0) {
        float tr = sqrtf(1.0f - p[9]);
        float pw = 1.0f;
        for (int k = 0; k <= 10; ++k) { s_trpow[k] = pw; pw *= tr; }
        s_nspike = 0;
        s_qnext  = NWAVES;
        s_rec[NIMG] = make_float4(0.0f, 0.0f, 0.0f, -1.0e6f);  // dummy
    }
    __syncthreads();

    const float rx = p[0], ry = p[1], rz = p[2];
    const float mx = p[3] * rx, my = p[4] * ry, mz = p[5] * rz;
    const float sx = p[6] * rx, sy = p[7] * ry, sz = p[8] * rz;
    const float K = 16000.0f / 343.0f;
    const float INV_PI = 0.31830988618379067154f;

    // ---- phase 1: per-image parameters + bucket histogram ----
    float4 rec[2];
    int ibkt[2]  = {0, 0};
    bool ivalid[2] = {false, false};

    for (int u = 0; u < 2; ++u) {
        int i = tid + u * NTHREADS;
        if (i < NIMG) {
            unsigned v = c_tab.v[i];
            int gx = (int)(v & 31u) - 10;
            int gy = (int)((v >> 5) & 31u) - 10;
            int gz = (int)((v >> 10) & 31u) - 10;
            int l1 = (int)(v >> 15);

            float ix = (gx & 1) ? rx * (float)(gx + 1) - sx : rx * (float)gx + sx;
            float iy = (gy & 1) ? ry * (float)(gy + 1) - sy : ry * (float)gy + sy;
            float iz = (gz & 1) ? rz * (float)(gz + 1) - sz : rz * (float)gz + sz;

            float dx = ix - mx, dy = iy - my, dz = iz - mz;
            float dist = sqrtf(dx * dx + dy * dy + dz * dz);

            float amp  = s_trpow[l1] * __builtin_amdgcn_rcpf(dist);
            float d    = dist * K;
            float dlc  = ceilf(d);
            float frac = dlc - d;                 // exact (Sterbenz)
            int   idlc = (int)dlc;
            int   base = idlc - PADI;

            if (base < RIRLEN) {
                if (frac == 0.0f) {
                    // integer-grid delay: exact single spike of amp at idlc
                    if (idlc < RIRLEN) {
                        int sp = atomicAdd(&s_nspike, 1);
                        if (sp < 64) { s_spike_idx[sp] = idlc; s_spike_amp[sp] = amp; }
                    }
                } else {
                    float spf = (frac < 1.0e-3f) ? frac : (sinpif(frac) * INV_PI);
                    float S   = amp * spf;
                    if (idlc & 1) S = -S;         // (-1)^dlc
                    float hS  = 0.5f * S;
                    float cd  = cospif(d * 0.025f);
                    float sd  = sinpif(d * 0.025f);
                    rec[u] = make_float4(hS, hS * cd, hS * sd, d);
                    ibkt[u]   = (base + 80) >> 4;
                    ivalid[u] = true;
                    atomicAdd(&s_hist[ibkt[u]], 1);
                }
            }
        }
    }
    __syncthreads();

    // ---- single-wave exclusive scan of the 505-bucket histogram ----
    if (tid < 64) {
        int base_i = tid * 8;
        int v[8], pre[8];
        int run = 0;
#pragma unroll
        for (int j = 0; j < 8; ++j) {
            v[j] = s_hist[base_i + j];            // padded entries are 0
            pre[j] = run;
            run += v[j];
        }
        int t = run;
#pragma unroll
        for (int d2 = 1; d2 < 64; d2 <<= 1) {
            int y = __shfl_up(t, d2);
            if (tid >= d2) t += y;
        }
        int excl = t - run;
#pragma unroll
        for (int j = 0; j < 8; ++j) {
            int idx = base_i + j;
            int sv  = excl + pre[j];              // exclusive prefix at idx
            s_start[idx] = sv;
            if (idx < NBKT) s_cursor[idx] = sv;
        }
    }
    __syncthreads();

    // ---- scatter records into bucket-sorted order ----
    for (int u = 0; u < 2; ++u) {
        if (ivalid[u]) {
            int pos = atomicAdd(&s_cursor[ibkt[u]], 1);
            s_rec[pos] = rec[u];
        }
    }
    __syncthreads();

    // ---- phase 2: gather. each wave serves TWO 128-sample tiles ----
    const int wave = tid >> 6;
    const int lane = tid & 63;
    const int h    = lane >> 5;
    const int l5   = lane & 31;
    const float sgn = (l5 & 1) ? -1.0f : 1.0f;    // (-1)^n, same for all 4 samples
    const float c32 = -0.80901699437494742410f;   // cos(0.8*pi)
    const float s32 =  0.58778525229247312917f;   // sin(0.8*pi)
    float* __restrict__ ob = out + (size_t)b * RIRLEN;

    int q = wave;
    while (q < NPAIRS) {
        const int t    = 2 * q + h;               // this half's tile (t=63 empty)
        const int n0   = (t << 7) + l5;           // lane's first sample
        const float fn0 = (float)n0;
        const float cn0 = cospif(fn0 * 0.025f), sn0 = sinpif(fn0 * 0.025f);
        const float cn1 = cn0 * c32 - sn0 * s32;  // n0+32
        const float sn1 = sn0 * c32 + cn0 * s32;
        const float cn2 = cn1 * c32 - sn1 * s32;  // n0+64
        const float sn2 = sn1 * c32 + cn1 * s32;
        const float cn3 = cn2 * c32 - sn2 * s32;  // n0+96
        const float sn3 = sn2 * c32 + cn2 * s32;

        // bucket window for tile t: [8t, 8t+13)  (max index 8*62+13=509)
        const int tA = 2 * q, tB = 2 * q + 1;
        const int loA = s_start[8 * tA];
        const int hiA = s_start[8 * tA + 13];
        int loB = 0, hiB = 0;
        if (tB < NTILE) { loB = s_start[8 * tB]; hiB = s_start[8 * tB + 13]; }
        const int lenA = hiA - loA, lenB = hiB - loB;
        const int lmin = (lenA < lenB) ? lenA : lenB;
        const int lmax = (lenA > lenB) ? lenA : lenB;
        const int lo   = h ? loB : loA;
        const int hi   = h ? hiB : hiA;

        float acc0 = 0.0f, acc1 = 0.0f, acc2 = 0.0f, acc3 = 0.0f;
        // main loop: both halves in-range, no select on the index.
        // paired-rcp: 1/x0=x1*rcp(x0*x1), 1/x1=x0*rcp(x0*x1); same for x2,x3.
#pragma clang loop unroll_count(4)
        for (int it = 0; it < lmin; ++it) {
            float4 r = s_rec[lo + it];
            float x0 = fn0 - r.w;                 // never 0 (d non-integer)
            float x1 = x0 + 32.0f;
            float x2 = x0 + 64.0f;
            float x3 = x0 + 96.0f;
            float pr01 = __builtin_amdgcn_rcpf(x0 * x1);
            float pr23 = __builtin_amdgcn_rcpf(x2 * x3);
            float t0 = fmaf(r.y, cn0, r.x); t0 = fmaf(r.z, sn0, t0);
            float t1 = fmaf(r.y, cn1, r.x); t1 = fmaf(r.z, sn1, t1);
            float t2 = fmaf(r.y, cn2, r.x); t2 = fmaf(r.z, sn2, t2);
            float t3 = fmaf(r.y, cn3, r.x); t3 = fmaf(r.z, sn3, t3);
            t0 = (fabsf(x0) < 40.0f) ? t0 : 0.0f; // hann support mask
            t1 = (fabsf(x1) < 40.0f) ? t1 : 0.0f;
            t2 = (fabsf(x2) < 40.0f) ? t2 : 0.0f;
            t3 = (fabsf(x3) < 40.0f) ? t3 : 0.0f;
            acc0 = fmaf(t0 * x1, pr01, acc0);
            acc1 = fmaf(t1 * x0, pr01, acc1);
            acc2 = fmaf(t2 * x3, pr23, acc2);
            acc3 = fmaf(t3 * x2, pr23, acc3);
        }
        // fixup: longer half continues, shorter half reads dummy record
        for (int it = lmin; it < lmax; ++it) {
            int k = lo + it;
            float4 r = s_rec[(k < hi) ? k : NIMG];
            float x0 = fn0 - r.w;
            float x1 = x0 + 32.0f;
            float x2 = x0 + 64.0f;
            float x3 = x0 + 96.0f;
            float pr01 = __builtin_amdgcn_rcpf(x0 * x1);
            float pr23 = __builtin_amdgcn_rcpf(x2 * x3);
            float t0 = fmaf(r.y, cn0, r.x); t0 = fmaf(r.z, sn0, t0);
            float t1 = fmaf(r.y, cn1, r.x); t1 = fmaf(r.z, sn1, t1);
            float t2 = fmaf(r.y, cn2, r.x); t2 = fmaf(r.z, sn2, t2);
            float t3 = fmaf(r.y, cn3, r.x); t3 = fmaf(r.z, sn3, t3);
            t0 = (fabsf(x0) < 40.0f) ? t0 : 0.0f;
            t1 = (fabsf(x1) < 40.0f) ? t1 : 0.0f;
            t2 = (fabsf(x2) < 40.0f) ? t2 : 0.0f;
            t3 = (fabsf(x3) < 40.0f) ? t3 : 0.0f;
            acc0 = fmaf(t0 * x1, pr01, acc0);
            acc1 = fmaf(t1 * x0, pr01, acc1);
            acc2 = fmaf(t2 * x3, pr23, acc2);
            acc3 = fmaf(t3 * x2, pr23, acc3);
        }
        if (n0      < RIRLEN) ob[n0]      = acc0 * sgn;
        if (n0 + 32 < RIRLEN) ob[n0 + 32] = acc1 * sgn;
        if (n0 + 64 < RIRLEN) ob[n0 + 64] = acc2 * sgn;
        if (n0 + 96 < RIRLEN) ob[n0 + 96] = acc3 * sgn;

        // steal next pair
        int nq;
        if (lane == 0) nq = atomicAdd(&s_qnext, 1);
        q = __shfl(nq, 0);
    }

    // ---- spikes (frac==0, rare): add after stores ----
    __syncthreads();
    int nsp = s_nspike; nsp = (nsp < 64) ? nsp : 64;
    if (tid < nsp) atomicAdd(&ob[s_spike_idx[tid]], s_spike_amp[tid]);

    // time-of-arrival
    if (tid == 0) {
        float dx = mx - sx, dy = my - sy, dz = mz - sz;
        out[(size_t)NB * RIRLEN + b] = 40.0f + sqrtf(dx * dx + dy * dy + dz * dz) * K;
    }
}

extern "C" void kernel_launch(void* const* d_in, const int* in_sizes, int n_in,
                              void* d_out, int out_size, void* d_ws, size_t ws_size,
                              hipStream_t stream) {
    const float* in = (const float*)d_in[0];
    float* out = (float*)d_out;
    rir_kernel<<<dim3(NB), dim3(NTHREADS), 0, stream>>>(in, out);
}

// Round 11
// 77.689 us; speedup vs baseline: 1.2497x; 1.2331x over previous
//
#include <hip/hip_runtime.h>
#include <math.h>

#define NB 256
#define NIMG 1561
#define RIRLEN 8000
#define PADI 40
#define NTHREADS 1024
#define NWAVES (NTHREADS / 64)
#define NBKT 505          // bucket = (base+80)>>4, base in [-40,7999] -> 2..504
#define NSTARTP 512       // s_start padded to 512 (entries >=505 = total)
#define NPAIR 63          // pairs of 64-sample streams; pair q = streams 2q,2q+1

// ---------------------------------------------------------------------------
// Compile-time image-lattice table: all g in [-10,10]^3 with |g|_1 <= 10,
// meshgrid(ij) lexicographic order. Packed:
//   bits 0-4: x+10, 5-9: y+10, 10-14: z+10, 15-19: |g|_1
// ---------------------------------------------------------------------------
struct ImgTab { unsigned int v[NIMG]; };

constexpr ImgTab build_tab() {
    ImgTab t{};
    int n = 0;
    for (int x = -10; x <= 10; ++x)
        for (int y = -10; y <= 10; ++y)
            for (int z = -10; z <= 10; ++z) {
                int ax = x < 0 ? -x : x;
                int ay = y < 0 ? -y : y;
                int az = z < 0 ? -z : z;
                int l1 = ax + ay + az;
                if (l1 <= 10) {
                    t.v[n++] = (unsigned)(x + 10) | ((unsigned)(y + 10) << 5) |
                               ((unsigned)(z + 10) << 10) | ((unsigned)l1 << 15);
                }
            }
    return t;
}

constexpr int tab_count() {
    int n = 0;
    for (int x = -10; x <= 10; ++x)
        for (int y = -10; y <= 10; ++y)
            for (int z = -10; z <= 10; ++z) {
                int ax = x < 0 ? -x : x;
                int ay = y < 0 ? -y : y;
                int az = z < 0 ? -z : z;
                if (ax + ay + az <= 10) ++n;
            }
    return n;
}
static_assert(tab_count() == NIMG, "image count mismatch");

__constant__ ImgTab c_tab = build_tab();

// Record per image (bucket-sorted): (A, B, C, d)
//   A = 0.5*S, B = 0.5*S*cos(pi*d/40), C = 0.5*S*sin(pi*d/40)
//   S = (-1)^dlc * amp * sin(pi*frac)/pi,  d = delay (exact, NON-integer)
// Tap at sample n: (-1)^n * (A + B*cos(pi*n/40) + C*sin(pi*n/40)) / (n-d),
// masked to |n-d| < 40.  frac==0 records are emitted as exact spikes instead.
__global__ __launch_bounds__(NTHREADS) void
rir_kernel(const float* __restrict__ in, float* __restrict__ out) {
    __shared__ float4 s_rec[NIMG + 1];   // +1 dummy (zero) record
    __shared__ float  s_trpow[11];
    __shared__ int    s_hist[NSTARTP];
    __shared__ int    s_start[NSTARTP];
    __shared__ int    s_cursor[NBKT];
    __shared__ int    s_qnext;
    __shared__ int    s_nspike;
    __shared__ int    s_spike_idx[64];
    __shared__ float  s_spike_amp[64];

    const int b   = blockIdx.x;
    const int tid = threadIdx.x;
    const float* p = in + b * 10;

    if (tid < NSTARTP) s_hist[tid] = 0;
    if (tid == 0) {
        float tr = sqrtf(1.0f - p[9]);
        float pw = 1.0f;
        for (int k = 0; k <= 10; ++k) { s_trpow[k] = pw; pw *= tr; }
        s_nspike = 0;
        s_qnext  = NWAVES;
        s_rec[NIMG] = make_float4(0.0f, 0.0f, 0.0f, -1.0e6f);  // dummy
    }
    __syncthreads();

    const float rx = p[0], ry = p[1], rz = p[2];
    const float mx = p[3] * rx, my = p[4] * ry, mz = p[5] * rz;
    const float sx = p[6] * rx, sy = p[7] * ry, sz = p[8] * rz;
    const float K = 16000.0f / 343.0f;
    const float INV_PI = 0.31830988618379067154f;

    // ---- phase 1: per-image parameters + bucket histogram ----
    float4 rec[2];
    int ibkt[2]  = {0, 0};
    bool ivalid[2] = {false, false};

    for (int u = 0; u < 2; ++u) {
        int i = tid + u * NTHREADS;
        if (i < NIMG) {
            unsigned v = c_tab.v[i];
            int gx = (int)(v & 31u) - 10;
            int gy = (int)((v >> 5) & 31u) - 10;
            int gz = (int)((v >> 10) & 31u) - 10;
            int l1 = (int)(v >> 15);

            float ix = (gx & 1) ? rx * (float)(gx + 1) - sx : rx * (float)gx + sx;
            float iy = (gy & 1) ? ry * (float)(gy + 1) - sy : ry * (float)gy + sy;
            float iz = (gz & 1) ? rz * (float)(gz + 1) - sz : rz * (float)gz + sz;

            float dx = ix - mx, dy = iy - my, dz = iz - mz;
            float dist = sqrtf(dx * dx + dy * dy + dz * dz);

            float amp  = s_trpow[l1] * __builtin_amdgcn_rcpf(dist);
            float d    = dist * K;
            float dlc  = ceilf(d);
            float frac = dlc - d;                 // exact (Sterbenz)
            int   idlc = (int)dlc;
            int   base = idlc - PADI;

            if (base < RIRLEN) {
                if (frac == 0.0f) {
                    // integer-grid delay: exact single spike of amp at idlc
                    if (idlc < RIRLEN) {
                        int sp = atomicAdd(&s_nspike, 1);
                        if (sp < 64) { s_spike_idx[sp] = idlc; s_spike_amp[sp] = amp; }
                    }
                } else {
                    float spf = (frac < 1.0e-3f) ? frac : (sinpif(frac) * INV_PI);
                    float S   = amp * spf;
                    if (idlc & 1) S = -S;         // (-1)^dlc
                    float hS  = 0.5f * S;
                    float cd  = cospif(d * 0.025f);
                    float sd  = sinpif(d * 0.025f);
                    rec[u] = make_float4(hS, hS * cd, hS * sd, d);
                    ibkt[u]   = (base + 80) >> 4;
                    ivalid[u] = true;
                    atomicAdd(&s_hist[ibkt[u]], 1);
                }
            }
        }
    }
    __syncthreads();

    // ---- single-wave exclusive scan of the 505-bucket histogram ----
    // lane l owns buckets [8l, 8l+8); local prefix + shfl_up wave scan.
    if (tid < 64) {
        int base_i = tid * 8;
        int v[8], pre[8];
        int run = 0;
#pragma unroll
        for (int j = 0; j < 8; ++j) {
            v[j] = s_hist[base_i + j];            // padded entries are 0
            pre[j] = run;
            run += v[j];
        }
        int t = run;
#pragma unroll
        for (int d2 = 1; d2 < 64; d2 <<= 1) {
            int y = __shfl_up(t, d2);
            if (tid >= d2) t += y;
        }
        int excl = t - run;
#pragma unroll
        for (int j = 0; j < 8; ++j) {
            int idx = base_i + j;
            int sv  = excl + pre[j];              // exclusive prefix at idx
            s_start[idx] = sv;
            if (idx < NBKT) s_cursor[idx] = sv;
        }
    }
    __syncthreads();

    // ---- scatter records into bucket-sorted order ----
    for (int u = 0; u < 2; ++u) {
        if (ivalid[u]) {
            int pos = atomicAdd(&s_cursor[ibkt[u]], 1);
            s_rec[pos] = rec[u];
        }
    }
    __syncthreads();

    // ---- phase 2: gather. each wave serves TWO 64-sample streams ----
    // lanes 0-31 -> stream 2q (h=0), lanes 32-63 -> stream 2q+1 (h=1);
    // each lane owns samples n0 and n0+32. One ds_read_b128 carries two
    // distinct addresses (2-way: free). Work-stealing over pairs.
    const int wave = tid >> 6;
    const int lane = tid & 63;
    const int h    = lane >> 5;
    const int l5   = lane & 31;
    const float sgn = (l5 & 1) ? -1.0f : 1.0f;    // (-1)^n, n parity == l5 parity
    const float c32 = -0.80901699437494742410f;   // cos(0.8*pi)
    const float s32 =  0.58778525229247312917f;   // sin(0.8*pi)
    float* __restrict__ ob = out + (size_t)b * RIRLEN;

    int q = wave;
    while (q < NPAIR) {
        const int n0 = (q << 7) + (h << 6) + l5;
        const int n1 = n0 + 32;
        const float fn0 = (float)n0;
        const float cn0 = cospif(fn0 * 0.025f), sn0 = sinpif(fn0 * 0.025f);
        const float cnn1 = cn0 * c32 - sn0 * s32; // cos(pi*n1/40)
        const float snn1 = sn0 * c32 + cn0 * s32; // sin(pi*n1/40)

        const int loA = s_start[8 * q];
        const int hiA = s_start[8 * q + 9];
        const int loB = s_start[8 * q + 4];
        const int hiB = s_start[8 * q + 13];
        const int lenA = hiA - loA, lenB = hiB - loB;
        const int lmin = (lenA < lenB) ? lenA : lenB;
        const int lmax = (lenA > lenB) ? lenA : lenB;
        const int lo   = h ? loB : loA;
        const int hi   = h ? hiB : hiA;

        float acc0 = 0.0f, acc1 = 0.0f;
        // main loop: both halves in-range, no select on the index.
        // shared-rcp trick: 1/x0 = x1*rcp(x0*x1), 1/x1 = x0*rcp(x0*x1)
        // (|x0*x1| in [~3e-6, 7.3e3], never 0 since d is non-integer).
#pragma clang loop unroll_count(8)
        for (int it = 0; it < lmin; ++it) {
            float4 r = s_rec[lo + it];
            float x0 = fn0 - r.w;                 // never 0 (d non-integer)
            float x1 = x0 + 32.0f;
            float pr = __builtin_amdgcn_rcpf(x0 * x1);
            float t0 = fmaf(r.y, cn0, r.x);  t0 = fmaf(r.z, sn0, t0);
            float t1 = fmaf(r.y, cnn1, r.x); t1 = fmaf(r.z, snn1, t1);
            t0 = (fabsf(x0) < 40.0f) ? t0 : 0.0f; // hann support mask
            t1 = (fabsf(x1) < 40.0f) ? t1 : 0.0f;
            acc0 = fmaf(t0 * x1, pr, acc0);
            acc1 = fmaf(t1 * x0, pr, acc1);
        }
        // fixup: longer half continues, shorter half reads dummy record
#pragma clang loop unroll_count(4)
        for (int it = lmin; it < lmax; ++it) {
            int k = lo + it;
            float4 r = s_rec[(k < hi) ? k : NIMG];
            float x0 = fn0 - r.w;
            float x1 = x0 + 32.0f;
            float pr = __builtin_amdgcn_rcpf(x0 * x1);
            float t0 = fmaf(r.y, cn0, r.x);  t0 = fmaf(r.z, sn0, t0);
            float t1 = fmaf(r.y, cnn1, r.x); t1 = fmaf(r.z, snn1, t1);
            t0 = (fabsf(x0) < 40.0f) ? t0 : 0.0f;
            t1 = (fabsf(x1) < 40.0f) ? t1 : 0.0f;
            acc0 = fmaf(t0 * x1, pr, acc0);
            acc1 = fmaf(t1 * x0, pr, acc1);
        }
        if (n0 < RIRLEN) ob[n0] = acc0 * sgn;
        if (n1 < RIRLEN) ob[n1] = acc1 * sgn;

        // steal next pair
        int nq;
        if (lane == 0) nq = atomicAdd(&s_qnext, 1);
        q = __shfl(nq, 0);
    }

    // ---- spikes (frac==0, rare): add after stores ----
    __syncthreads();
    int nsp = s_nspike; nsp = (nsp < 64) ? nsp : 64;
    if (tid < nsp) atomicAdd(&ob[s_spike_idx[tid]], s_spike_amp[tid]);

    // time-of-arrival
    if (tid == 0) {
        float dx = mx - sx, dy = my - sy, dz = mz - sz;
        out[(size_t)NB * RIRLEN + b] = 40.0f + sqrtf(dx * dx + dy * dy + dz * dz) * K;
    }
}

extern "C" void kernel_launch(void* const* d_in, const int* in_sizes, int n_in,
                              void* d_out, int out_size, void* d_ws, size_t ws_size,
                              hipStream_t stream) {
    const float* in = (const float*)d_in[0];
    float* out = (float*)d_out;
    rir_kernel<<<dim3(NB), dim3(NTHREADS), 0, stream>>>(in, out);
}